// Round 3
// baseline (514.804 us; speedup 1.0000x reference)
//
#include <hip/hip_runtime.h>
#include <hip/hip_bf16.h>
#include <stdint.h>

typedef unsigned short u16;
typedef __bf16 bf16_8 __attribute__((ext_vector_type(8)));
typedef float f32x4 __attribute__((ext_vector_type(4)));

#define SEQ 2048
#define DIM 4096
#define NH 32
#define NKV 8
#define HD 128
// 1/sqrt(128) * log2(e)  -- exp2-based softmax, scale folded into Q epilogue
#define QSCALE_LOG2E 0.12753785222167917f

__device__ inline u16 f2bf(float f) {
    unsigned int u = __float_as_uint(f);
    unsigned int r = (u + 0x7fffu + ((u >> 16) & 1u)) >> 16;
    return (u16)r;
}

__device__ inline void async16(const void* g, void* l) {
    __builtin_amdgcn_global_load_lds(
        (const __attribute__((address_space(1))) void*)g,
        (__attribute__((address_space(3))) void*)l, 16, 0, 0);
}

// ---------------- fused fp32 -> bf16 cast of all 5 tensors ----------------
__global__ __launch_bounds__(256) void cast_all(const float* __restrict__ x,
                                                const float* __restrict__ wq,
                                                const float* __restrict__ wk,
                                                const float* __restrict__ wv,
                                                const float* __restrict__ wo,
                                                u16* __restrict__ dst) {
    size_t i4 = (size_t)blockIdx.x * 256 + threadIdx.x;  // float4 group index
    size_t e = i4 * 4;                                   // element index
    const float* src;
    size_t off;  // segment start (elements)
    if (e < 8388608ull)       { src = x;  off = 0; }
    else if (e < 25165824ull) { src = wq; off = 8388608ull; }
    else if (e < 29360128ull) { src = wk; off = 25165824ull; }
    else if (e < 33554432ull) { src = wv; off = 29360128ull; }
    else                      { src = wo; off = 33554432ull; }
    float4 v = ((const float4*)src)[i4 - off / 4];
    ushort4 o;
    o.x = f2bf(v.x); o.y = f2bf(v.y); o.z = f2bf(v.z); o.w = f2bf(v.w);
    ((ushort4*)dst)[i4] = o;
}

// ===== 2-barrier 4-phase GEMM: C[M,N] = A[M,K]*B[N,K]^T (bf16, fp32 acc) ===
// MODE 1 (QKV+RoPE): BM=256 BN=256, 8 waves 2Mx4N, wave tile 128x64, acc[8][4].
// MODE 0 (out-proj): BM=256 BN=128, 8 waves 4Mx2N, wave tile  64x64, acc[4][4]
//                    -> grid 32x8 = 256 blocks = full chip.
// Per K-tile, 4 phases; phase q = { pre: ds_read this phase's frags (B all at
// ph0, A-quadrant q); issue 1 stage unit of tile t+1; [counted vmcnt] } then
// s_barrier; lgkmcnt(0); setprio(1); MFMA cluster; setprio(0); s_barrier.
// Stage units are reader-aligned per wave (B share split B1,B2; A share split
// a1=rows covering q0/q1, a2=rows covering q2/q3).  Per-wave vmcnt ledger:
//   ph1: vmcnt(4) drains a2(t)        (needed by q2/q3 reads after ph1 bar)
//   ph3: vmcnt(2) drains B+a1(t+1)    (needed by ph0 reads after ph3 bar)
// never vmcnt(0) in the main loop; cross-wave guarantee = own-vmcnt + barrier
// (every wave's units sit at the same ledger positions).
template <int MODE>
__global__ __launch_bounds__(512, 2) void gemm8p(const u16* __restrict__ A,
                                                 const u16* __restrict__ B,
                                                 void* __restrict__ C0,
                                                 void* __restrict__ C1,
                                                 void* __restrict__ C2,
                                                 const float* __restrict__ fc,
                                                 const float* __restrict__ fs,
                                                 int M, int N, int K) {
    constexpr int BM = 256;
    constexpr int BN = (MODE == 1) ? 256 : 128;
    constexpr int WCN = (MODE == 1) ? 4 : 2;   // waves along N
    constexpr int WM = (MODE == 1) ? 128 : 64; // wave tile M
    constexpr int AI = WM / 16;                // acc rows: 8 / 4
    constexpr int PAI = AI / 4;                // acc rows per phase: 2 / 1
    constexpr int NBU = (MODE == 1) ? 2 : 1;   // B stage units per wave
    constexpr int NU = NBU + 2;                // total units: 4 / 3

    extern __shared__ u16 sm[];
    u16* As = sm;                    // [2][BM][64]
    u16* Bs = sm + 2 * BM * 64;      // [2][BN][64]

    const int tid = threadIdx.x;
    const int lane = tid & 63;
    const int wid = tid >> 6;
    const int wr = wid / WCN;
    const int wc = wid % WCN;
    const int quad = lane >> 4;
    const int l16 = lane & 15;
    const int l8hi = lane >> 3;  // row offset within an 8-row load group
    const int l8lo = lane & 7;   // 16B slot within the row

    // XCD-aware bijective block swizzle (nwg % 8 == 0 for both launches)
    const int nwg = gridDim.x * gridDim.y;
    int id = blockIdx.y * gridDim.x + blockIdx.x;
    int swz = (id & 7) * (nwg >> 3) + (id >> 3);
    const int bm = (swz / gridDim.x) * BM;
    const int bn = (swz % gridDim.x) * BN;

    f32x4 acc[AI][4] = {};

    // stage unit u (2 x async16, 16 rows) of tile t.  chunk pre-swizzle:
    // slot=lane&7, row&7=lane>>3 -> global chunk = (lane&7)^(lane>>3).
    auto stage_unit = [&](int t, int u) {
        const int buf = t & 1;
        const int k0 = t << 6;
        const int ch = l8lo ^ l8hi;
        if (u < NBU) {  // B share: quarter wc staged by the WRN waves sharing wc
            int row0 = (MODE == 1) ? (wc * 64 + wr * 32 + u * 16)
                                   : (wc * 64 + wr * 16);
#pragma unroll
            for (int r = 0; r < 2; ++r) {
                int R = row0 + r * 8;
                const u16* g = &B[(size_t)(bn + R + l8hi) * K + k0 + ch * 8];
                async16(g, (void*)&Bs[buf * (BN * 64) + R * 64 + lane * 8]);
            }
        } else {        // A share: panel wr staged by the WCN waves sharing wr;
                        // a1 covers panel rows [0,WM/2), a2 covers [WM/2,WM)
            int q = u - NBU;
            int row0 = (MODE == 1) ? (wr * 128 + q * 64 + wc * 16)
                                   : (wr * 64 + q * 32 + wc * 16);
#pragma unroll
            for (int r = 0; r < 2; ++r) {
                int R = row0 + r * 8;
                const u16* g = &A[(size_t)(bm + R + l8hi) * K + k0 + ch * 8];
                async16(g, (void*)&As[buf * (BM * 64) + R * 64 + lane * 8]);
            }
        }
    };

    const int chsw = l16 & 7;
    bf16_8 bfr[4][2];  // wave's 8 B-frags, read at ph0, live across the tile

#define PHASE(Q, STAGE_STMT, VM_STMT)                                             \
    {                                                                             \
        const int buf = t & 1;                                                    \
        const u16* as = As + buf * (BM * 64) + wr * (WM * 64);                    \
        const u16* bs = Bs + buf * (BN * 64) + wc * (64 * 64);                    \
        if (Q == 0) {                                                             \
            _Pragma("unroll")                                                     \
            for (int j = 0; j < 4; ++j)                                           \
                _Pragma("unroll")                                                 \
                for (int kk = 0; kk < 2; ++kk)                                    \
                    bfr[j][kk] = *(const bf16_8*)&bs[(j * 16 + l16) * 64 +        \
                                                     (((kk * 4 + quad) ^ chsw) << 3)]; \
        }                                                                         \
        bf16_8 afr[PAI][2];                                                       \
        _Pragma("unroll")                                                         \
        for (int i = 0; i < PAI; ++i)                                             \
            _Pragma("unroll")                                                     \
            for (int kk = 0; kk < 2; ++kk)                                        \
                afr[i][kk] = *(const bf16_8*)&as[((Q * PAI + i) * 16 + l16) * 64 + \
                                                 (((kk * 4 + quad) ^ chsw) << 3)]; \
        STAGE_STMT;                                                               \
        VM_STMT;                                                                  \
        asm volatile("s_barrier" ::: "memory");                                   \
        asm volatile("s_waitcnt lgkmcnt(0)" ::: "memory");                        \
        __builtin_amdgcn_s_setprio(1);                                            \
        _Pragma("unroll")                                                         \
        for (int kk = 0; kk < 2; ++kk)                                            \
            _Pragma("unroll")                                                     \
            for (int i = 0; i < PAI; ++i)                                         \
                _Pragma("unroll")                                                 \
                for (int j = 0; j < 4; ++j)                                       \
                    acc[Q * PAI + i][j] = __builtin_amdgcn_mfma_f32_16x16x32_bf16( \
                        afr[i][kk], bfr[j][kk], acc[Q * PAI + i][j], 0, 0, 0);    \
        __builtin_amdgcn_s_setprio(0);                                            \
        asm volatile("s_barrier" ::: "memory");                                   \
    }

    const int NT = K >> 6;  // 64 for K=4096

    // prologue: stage tile 0 (all units, in ledger order), drain all but a2
#pragma unroll
    for (int u = 0; u < NU; ++u) stage_unit(0, u);
    asm volatile("s_waitcnt vmcnt(2)" ::: "memory");
    asm volatile("s_barrier" ::: "memory");

    for (int t = 0; t < NT - 1; ++t) {
        PHASE(0, stage_unit(t + 1, 0), )
        PHASE(1, stage_unit(t + 1, 1), asm volatile("s_waitcnt vmcnt(4)" ::: "memory"))
        PHASE(2, stage_unit(t + 1, 2), )
        PHASE(3, if (NU > 3) stage_unit(t + 1, 3),
                 asm volatile("s_waitcnt vmcnt(2)" ::: "memory"))
    }
    {   // last tile: no staging; only remaining in-flight unit is its a2
        const int t = NT - 1;
        PHASE(0, , )
        PHASE(1, , asm volatile("s_waitcnt vmcnt(0)" ::: "memory"))
        PHASE(2, , )
        PHASE(3, , )
    }
#undef PHASE

    const int wm = wr * WM;
    const int wn = wc * 64;

    if (MODE == 0) {
        float* Cf = (float*)C0;
#pragma unroll
        for (int i = 0; i < AI; ++i)
#pragma unroll
            for (int j = 0; j < 4; ++j)
#pragma unroll
                for (int r = 0; r < 4; ++r)
                    Cf[(size_t)(bm + wm + i * 16 + quad * 4 + r) * N + (bn + wn + j * 16 + l16)] =
                        acc[i][j][r];
    } else {
        // QKV routing; bn is a multiple of 256 so the whole block takes one branch
        u16* Qb = (u16*)C0;
        u16* Kb = (u16*)C1;
        u16* Vt = (u16*)C2;
        if (bn < 5120) {
            const bool isQ = bn < 4096;
            const float osc = isQ ? QSCALE_LOG2E : 1.0f;
#pragma unroll
            for (int i = 0; i < AI; ++i)
#pragma unroll
                for (int j = 0; j < 4; ++j) {
                    int n = bn + wn + j * 16 + l16;
                    int pp = (n & 127) >> 1;
                    bool odd = (l16 & 1);
#pragma unroll
                    for (int r = 0; r < 4; ++r) {
                        int m = bm + wm + i * 16 + quad * 4 + r;
                        float v = acc[i][j][r];
                        float u = __shfl_xor(v, 1);
                        float c = fc[m * 64 + pp];
                        float s = fs[m * 64 + pp];
                        float o = (odd ? (u * s + v * c) : (v * c - u * s)) * osc;
                        if (isQ)
                            Qb[(size_t)m * 4096 + n] = f2bf(o);
                        else
                            Kb[(size_t)m * 1024 + (n - 4096)] = f2bf(o);
                    }
                }
        } else {
            // V range: store transposed (d-major), no rope
#pragma unroll
            for (int i = 0; i < AI; ++i)
#pragma unroll
                for (int j = 0; j < 4; ++j) {
                    int n = bn + wn + j * 16 + l16;
                    ushort4 o;
                    o.x = f2bf(acc[i][j][0]);
                    o.y = f2bf(acc[i][j][1]);
                    o.z = f2bf(acc[i][j][2]);
                    o.w = f2bf(acc[i][j][3]);
                    *(ushort4*)&Vt[(size_t)(n - 5120) * SEQ + (bm + wm + i * 16 + quad * 4)] = o;
                }
        }
    }
}

// ---------------- Flash attention, S^T formulation (unchanged) ----------------
__global__ __launch_bounds__(256, 4) void attn_k(const u16* __restrict__ Q,
                                                 const u16* __restrict__ Kb,
                                                 const u16* __restrict__ Vt,
                                                 u16* __restrict__ Y) {
    __shared__ u16 Ks[64 * 128];   // swizzled: 16B chunks, slot = c ^ (row&15)
    __shared__ u16 Vs[128 * 64];   // swizzled: 16B chunks, slot = c ^ (row&7)
    __shared__ u16 Ps[4 * 16 * 64];// per-wave 2 KB; 8B chunks, c' = c ^ ((l16&7)<<1)
    const int tid = threadIdx.x;
    const int lane = tid & 63;
    const int w = tid >> 6;
    const int quad = lane >> 4;
    const int l16 = lane & 15;
    const int id = blockIdx.x;
    const int qt = 31 - (id >> 5);   // LPT: longest blocks first
    const int h = id & 31;
    const int kvh = h >> 2;
    const size_t qrow0 = (size_t)qt * 64;

    bf16_8 qf[4];
#pragma unroll
    for (int ks = 0; ks < 4; ++ks)
        qf[ks] = *(const bf16_8*)&Q[(qrow0 + w * 16 + l16) * DIM + h * HD + ks * 32 + quad * 8];

    f32x4 po[8] = {};    // 16 x 128 unnormalized output accumulator
    float lsum = 0.f;    // per-lane partial row sum for q-row l16

    char* psbase = (char*)Ps + w * 2048 + l16 * 128;  // this lane's P row
    const int sw = (l16 & 7) << 1;                    // 8B-chunk swizzle

    for (int kt = 0; kt <= qt; ++kt) {
#pragma unroll
        for (int r = 0; r < 4; ++r) {
            int S = r * 256 + tid;  // 0..1023
            {
                int row = S >> 4, slot = S & 15;
                int chunk = slot ^ (row & 15);
                const char* g = (const char*)Kb +
                    (((size_t)kt * 64 + row) * 1024 + kvh * HD + chunk * 8) * 2;
                async16(g, (char*)Ks + S * 16);
            }
            {
                int row = S >> 3, slot = S & 7;
                int chunk = slot ^ (row & 7);
                const char* g = (const char*)Vt +
                    (((size_t)(kvh * HD + row)) * SEQ + kt * 64 + chunk * 8) * 2;
                async16(g, (char*)Vs + S * 16);
            }
        }
        __syncthreads();

        f32x4 sc[4] = {};
#pragma unroll
        for (int ks = 0; ks < 4; ++ks)
#pragma unroll
            for (int jb = 0; jb < 4; ++jb) {
                bf16_8 kb = *(const bf16_8*)&Ks[(jb * 16 + l16) * 128 + ((ks * 4 + quad) ^ l16) * 8];
                sc[jb] = __builtin_amdgcn_mfma_f32_16x16x32_bf16(kb, qf[ks], sc[jb], 0, 0, 0);
            }

        float pv[4][4];
#pragma unroll
        for (int jb = 0; jb < 4; ++jb)
#pragma unroll
            for (int r = 0; r < 4; ++r)
                pv[jb][r] = exp2f(sc[jb][r]);

        if (kt == qt) {  // wave-uniform: mask k > q on the diagonal tile
            int qloc = w * 16 + l16;
#pragma unroll
            for (int jb = 0; jb < 4; ++jb)
#pragma unroll
                for (int r = 0; r < 4; ++r)
                    if (jb * 16 + quad * 4 + r > qloc) pv[jb][r] = 0.f;
        }

#pragma unroll
        for (int jb = 0; jb < 4; ++jb) {
            lsum += (pv[jb][0] + pv[jb][1]) + (pv[jb][2] + pv[jb][3]);
            ushort4 pk;
            pk.x = f2bf(pv[jb][0]);
            pk.y = f2bf(pv[jb][1]);
            pk.z = f2bf(pv[jb][2]);
            pk.w = f2bf(pv[jb][3]);
            int c = jb * 4 + quad;
            *(ushort4*)(psbase + ((c ^ sw) << 3)) = pk;
        }

#pragma unroll
        for (int ks = 0; ks < 2; ++ks) {
            int c = ks * 8 + quad * 2;
            bf16_8 pf = *(const bf16_8*)(psbase + ((c ^ sw) << 3));
#pragma unroll
            for (int n = 0; n < 8; ++n) {
                bf16_8 vf = *(const bf16_8*)&Vs[(n * 16 + l16) * 64 + (((ks * 4 + quad) ^ (l16 & 7))) * 8];
                po[n] = __builtin_amdgcn_mfma_f32_16x16x32_bf16(pf, vf, po[n], 0, 0, 0);
            }
        }
        __syncthreads();
    }

    lsum += __shfl_xor(lsum, 16);
    lsum += __shfl_xor(lsum, 32);
    float inv = 1.f / lsum;
#pragma unroll
    for (int r = 0; r < 4; ++r) {
        float invr = __shfl(inv, quad * 4 + r);
        size_t row = qrow0 + w * 16 + quad * 4 + r;
#pragma unroll
        for (int n = 0; n < 8; ++n)
            Y[row * DIM + h * HD + n * 16 + l16] = f2bf(po[n][r] * invr);
    }
}

extern "C" void kernel_launch(void* const* d_in, const int* in_sizes, int n_in,
                              void* d_out, int out_size, void* d_ws, size_t ws_size,
                              hipStream_t stream) {
    const float* x  = (const float*)d_in[0];
    const float* wq = (const float*)d_in[1];
    const float* wk = (const float*)d_in[2];
    const float* wv = (const float*)d_in[3];
    const float* wo = (const float*)d_in[4];
    const float* fc = (const float*)d_in[5];
    const float* fs = (const float*)d_in[6];

    char* ws = (char*)d_ws;
    const size_t MB = 1u << 20;
    u16* xb    = (u16*)(ws);             // 2048x4096 bf16       (16 MB)
    u16* wqkvb = (u16*)(ws + 16 * MB);   // 6144x4096 (wq|wk|wv) (48 MB)
    u16* wob   = (u16*)(ws + 64 * MB);   // 4096x4096            (32 MB)
    u16* Qb    = (u16*)(ws + 96 * MB);   // 2048x4096            (16 MB)
    u16* Kb    = (u16*)(ws + 112 * MB);  // 2048x1024            (4 MB)
    u16* Vtb   = (u16*)(ws + 116 * MB);  // 1024x2048 (V^T)      (4 MB)
    u16* Yb    = (u16*)(ws + 120 * MB);  // 2048x4096            (16 MB)

    const int sm1 = (2 * 256 * 64 + 2 * 256 * 64) * 2;  // 128 KB (MODE 1)
    const int sm0 = (2 * 256 * 64 + 2 * 128 * 64) * 2;  //  96 KB (MODE 0)
    static int inited = 0;
    if (!inited) {
        hipFuncSetAttribute(reinterpret_cast<const void*>(&gemm8p<1>),
                            hipFuncAttributeMaxDynamicSharedMemorySize, sm1);
        hipFuncSetAttribute(reinterpret_cast<const void*>(&gemm8p<0>),
                            hipFuncAttributeMaxDynamicSharedMemorySize, sm0);
        inited = 1;
    }

    // single fused cast: [x | wq | wk | wv | wo] -> bf16 at ws[0..96MB)
    cast_all<<<49152, 256, 0, stream>>>(x, wq, wk, wv, wo, (u16*)ws);

    // fused QKV projection + RoPE (+ Q pre-scale incl. log2e) epilogue
    gemm8p<1><<<dim3(24, 8), 512, sm1, stream>>>(xb, wqkvb, Qb, Kb, Vtb, fc, fs,
                                                 2048, 6144, 4096);

    // attention (LPT-ordered 1D grid)
    attn_k<<<dim3(1024), 256, 0, stream>>>(Qb, Kb, Vtb, Yb);

    // output projection -> fp32 d_out (BM=256, BN=128 -> 256 blocks, full chip)
    gemm8p<0><<<dim3(32, 8), 512, sm0, stream>>>(Yb, wob, (float*)d_out, nullptr, nullptr,
                                                 nullptr, nullptr, 2048, 4096, 4096);
}

// Round 4
// 477.077 us; speedup vs baseline: 1.0791x; 1.0791x over previous
//
#include <hip/hip_runtime.h>
#include <hip/hip_bf16.h>
#include <stdint.h>

typedef unsigned short u16;
typedef __bf16 bf16_8 __attribute__((ext_vector_type(8)));
typedef float f32x4 __attribute__((ext_vector_type(4)));

#define SEQ 2048
#define DIM 4096
#define NH 32
#define NKV 8
#define HD 128
// 1/sqrt(128) * log2(e)  -- exp2-based softmax, scale folded into Q epilogue
#define QSCALE_LOG2E 0.12753785222167917f

__device__ inline u16 f2bf(float f) {
    unsigned int u = __float_as_uint(f);
    unsigned int r = (u + 0x7fffu + ((u >> 16) & 1u)) >> 16;
    return (u16)r;
}

__device__ inline void async16(const void* g, void* l) {
    __builtin_amdgcn_global_load_lds(
        (const __attribute__((address_space(1))) void*)g,
        (__attribute__((address_space(3))) void*)l, 16, 0, 0);
}

// ---------------- fused fp32 -> bf16 cast of all 5 tensors ----------------
__global__ __launch_bounds__(256) void cast_all(const float* __restrict__ x,
                                                const float* __restrict__ wq,
                                                const float* __restrict__ wk,
                                                const float* __restrict__ wv,
                                                const float* __restrict__ wo,
                                                u16* __restrict__ dst) {
    size_t i4 = (size_t)blockIdx.x * 256 + threadIdx.x;  // float4 group index
    size_t e = i4 * 4;                                   // element index
    const float* src;
    size_t off;  // segment start (elements)
    if (e < 8388608ull)       { src = x;  off = 0; }
    else if (e < 25165824ull) { src = wq; off = 8388608ull; }
    else if (e < 29360128ull) { src = wk; off = 25165824ull; }
    else if (e < 33554432ull) { src = wv; off = 29360128ull; }
    else                      { src = wo; off = 33554432ull; }
    float4 v = ((const float4*)src)[i4 - off / 4];
    ushort4 o;
    o.x = f2bf(v.x); o.y = f2bf(v.y); o.z = f2bf(v.z); o.w = f2bf(v.w);
    ((ushort4*)dst)[i4] = o;
}

// ===== progressive-retire 2-tile-deep pipelined GEMM  C = A * B^T (bf16) ====
// MODE 1 (QKV+RoPE): BM=256 BN=256, 8 waves 2Mx4N, wave 128x64, acc[8][4].
//   Phases = i-pairs (4/tile, 16 MFMA each). B-frags read ONCE @ph0 into 32
//   held VGPRs; A 4xb128 per phase.  16KB regions retire: B01@ph0, B23@ph0,
//   A-lo@ph1, A-hi@ph3.  Stage stream (1 unit/phase, 2 loads/thread/unit):
//     ph0: A-hi(t+1) [other buf, retired ph3(t-1)]
//     ph1: B01(t+2)  [same buf, retired ph0(t)]
//     ph2: B23(t+2)  [retired ph0(t)]
//     ph3: A-lo(t+2) [retired ph1(t)]
//   Ledger (loads): vmcnt(10)@ph1 guards A-hi(t) (lead 5 phases);
//   vmcnt(8)@ph3 guards {B01,B23,A-lo}(t+1) (lead 4-6 phases). Never <8 in
//   the main loop. Prologue: 7 units then vmcnt(6) (== m201's 4+3/vmcnt(6)).
//   Race-freedom: a unit staged at phase p overwrites a region whose reads
//   all retired before phase p-1's closing barrier (reads' consumers are in
//   the MFMA cluster, so lgkm waits complete before that barrier).
// MODE 0 (out-proj): BM=128 BN=256 -> grid 16x16 = 256 blocks (full chip),
//   8 waves 2Mx4N, wave 64x64, acc[4][4]. 2 phases/tile (j-halves, 16 MFMA).
//   A (one 16KB unit) read @ph0 into 32 held VGPRs; B01@ph0, B23@ph1.
//   Stage: ph0: B23(t+1) [other buf]; ph1: A(t+2)+B01(t+2) [same buf].
//   Waits vmcnt(6)@ph0 and vmcnt(6)@ph1; leads 2 phases.
template <int MODE>
__global__ __launch_bounds__(512, 2) void gemm8p(const u16* __restrict__ A,
                                                 const u16* __restrict__ B,
                                                 void* __restrict__ C0,
                                                 void* __restrict__ C1,
                                                 void* __restrict__ C2,
                                                 const float* __restrict__ fc,
                                                 const float* __restrict__ fs,
                                                 int M, int N, int K) {
    constexpr int BM = (MODE == 1) ? 256 : 128;
    constexpr int BN = 256;
    constexpr int WM = (MODE == 1) ? 128 : 64;  // wave tile M (x64 N)
    constexpr int AI = WM / 16;                 // acc rows: 8 / 4

    extern __shared__ u16 sm[];
    u16* As = sm;                    // [2][BM][64]
    u16* Bs = sm + 2 * BM * 64;      // [2][256][64]

    const int tid = threadIdx.x;
    const int lane = tid & 63;
    const int wid = tid >> 6;
    const int wr = wid >> 2;         // 0..1
    const int wc = wid & 3;          // 0..3
    const int quad = lane >> 4;
    const int l16 = lane & 15;

    // XCD-aware bijective block swizzle (nwg = 192 / 256, both % 8 == 0)
    const int nwg = gridDim.x * gridDim.y;
    int id = blockIdx.y * gridDim.x + blockIdx.x;
    int swz = (id & 7) * (nwg >> 3) + (id >> 3);
    const int bm = (swz / gridDim.x) * BM;
    const int bn = (swz % gridDim.x) * BN;

    f32x4 acc[AI][4] = {};

    // ---- stage helpers: one 16KB unit = 2 x async16 per thread.  chunk
    // pre-swizzle: global chunk (S&7)^(row&7) lands at slot S&7 (phys&7 ==
    // row&7 for every region mapping below, matching the read-side XOR). ----
    auto stB = [&](int t, int half) {   // B01 (half=0) / B23 (half=1):
        const int buf = t & 1;          // rows {wc*64 + half*32 + [0,32)}
        const int k0 = t << 6;
#pragma unroll
        for (int r = 0; r < 2; ++r) {
            int S = r * 512 + tid;
            int row = S >> 3;           // 0..127
            int phys = half * 32 + (row >> 5) * 64 + (row & 31);
            int ch = (S & 7) ^ (row & 7);
            const u16* g = &B[(size_t)(bn + phys) * K + k0 + ch * 8];
            async16(g, (void*)&Bs[buf * (256 * 64) + phys * 64 + (S & 7) * 8]);
        }
    };
    auto stA = [&](int t, int half) {   // MODE1: A-lo/A-hi = panel rows
        const int buf = t & 1;          // {wr*128 + half*64 + [0,64)}
        const int k0 = t << 6;
#pragma unroll
        for (int r = 0; r < 2; ++r) {
            int S = r * 512 + tid;
            int row = S >> 3;
            int phys = half * 64 + (row & 63) + (row >> 6) * 128;
            int ch = (S & 7) ^ (row & 7);
            const u16* g = &A[(size_t)(bm + phys) * K + k0 + ch * 8];
            async16(g, (void*)&As[buf * (BM * 64) + phys * 64 + (S & 7) * 8]);
        }
    };
    auto stA0 = [&](int t) {            // MODE0: whole 128-row A tile
        const int buf = t & 1;
        const int k0 = t << 6;
#pragma unroll
        for (int r = 0; r < 2; ++r) {
            int S = r * 512 + tid;
            int row = S >> 3;
            int ch = (S & 7) ^ (row & 7);
            const u16* g = &A[(size_t)(bm + row) * K + k0 + ch * 8];
            async16(g, (void*)&As[buf * (BM * 64) + row * 64 + (S & 7) * 8]);
        }
    };

    const int chsw = l16 & 7;
    const int NT = K >> 6;  // 64

#define VMW(n) asm volatile("s_waitcnt vmcnt(" #n ")" ::: "memory")
#define BAR() asm volatile("s_barrier" ::: "memory")

    if constexpr (MODE == 1) {
        bf16_8 bh[4][2];  // B-frags held across the tile's 4 phases

#define M1PHASE(T, P, STAGE_STMT, VM_STMT)                                      \
    {                                                                           \
        const u16* as = As + ((T) & 1) * (BM * 64) + wr * (128 * 64);           \
        const u16* bs = Bs + ((T) & 1) * (256 * 64) + wc * (64 * 64);           \
        bf16_8 afr[2][2];                                                       \
        _Pragma("unroll") for (int i = 0; i < 2; ++i)                           \
        _Pragma("unroll") for (int kk = 0; kk < 2; ++kk)                        \
            afr[i][kk] = *(const bf16_8*)&as[(((P) * 2 + i) * 16 + l16) * 64 +  \
                                             (((kk * 4 + quad) ^ chsw) << 3)];  \
        if ((P) == 0) {                                                         \
            _Pragma("unroll") for (int j = 0; j < 4; ++j)                       \
            _Pragma("unroll") for (int kk = 0; kk < 2; ++kk)                    \
                bh[j][kk] = *(const bf16_8*)&bs[(j * 16 + l16) * 64 +           \
                                             (((kk * 4 + quad) ^ chsw) << 3)];  \
        }                                                                       \
        STAGE_STMT;                                                             \
        VM_STMT;                                                                \
        BAR();                                                                  \
        __builtin_amdgcn_s_setprio(1);                                          \
        _Pragma("unroll") for (int kk = 0; kk < 2; ++kk)                        \
        _Pragma("unroll") for (int i = 0; i < 2; ++i)                           \
        _Pragma("unroll") for (int j = 0; j < 4; ++j)                           \
            acc[(P) * 2 + i][j] = __builtin_amdgcn_mfma_f32_16x16x32_bf16(      \
                afr[i][kk], bh[j][kk], acc[(P) * 2 + i][j], 0, 0, 0);           \
        __builtin_amdgcn_s_setprio(0);                                          \
        BAR();                                                                  \
    }

        // prologue: tile0 {B01,B23,Alo,Ahi} + tile1 {B01,B23,Alo} = 7 units
        stB(0, 0); stB(0, 1); stA(0, 0); stA(0, 1);
        stB(1, 0); stB(1, 1); stA(1, 0);
        VMW(6);   // tile0 complete (3 newer units in flight)
        BAR();

        for (int t = 0; t < NT - 2; ++t) {
            M1PHASE(t, 0, stA(t + 1, 1), )
            M1PHASE(t, 1, stB(t + 2, 0), VMW(10))
            M1PHASE(t, 2, stB(t + 2, 1), )
            M1PHASE(t, 3, stA(t + 2, 0), VMW(8))
        }
        {   // t = NT-2: stage only A-hi(NT-1); waits shrink per ledger
            const int t = NT - 2;
            M1PHASE(t, 0, stA(NT - 1, 1), )
            M1PHASE(t, 1, , VMW(8))
            M1PHASE(t, 2, , )
            M1PHASE(t, 3, , VMW(2))
        }
        {   // t = NT-1: no staging; final drain at ph1
            const int t = NT - 1;
            M1PHASE(t, 0, , )
            M1PHASE(t, 1, , VMW(0))
            M1PHASE(t, 2, , )
            M1PHASE(t, 3, , )
        }
#undef M1PHASE
    } else {
        bf16_8 ah[4][2];  // A-frags held across the tile's 2 phases

#define M0PHASE(T, P, STAGE_STMT, VM_STMT)                                      \
    {                                                                           \
        const u16* as = As + ((T) & 1) * (BM * 64) + wr * (64 * 64);            \
        const u16* bs = Bs + ((T) & 1) * (256 * 64) + wc * (64 * 64);           \
        if ((P) == 0) {                                                         \
            _Pragma("unroll") for (int i = 0; i < 4; ++i)                       \
            _Pragma("unroll") for (int kk = 0; kk < 2; ++kk)                    \
                ah[i][kk] = *(const bf16_8*)&as[(i * 16 + l16) * 64 +           \
                                             (((kk * 4 + quad) ^ chsw) << 3)];  \
        }                                                                       \
        bf16_8 bfr[2][2];                                                       \
        _Pragma("unroll") for (int j = 0; j < 2; ++j)                           \
        _Pragma("unroll") for (int kk = 0; kk < 2; ++kk)                        \
            bfr[j][kk] = *(const bf16_8*)&bs[(((P) * 2 + j) * 16 + l16) * 64 +  \
                                             (((kk * 4 + quad) ^ chsw) << 3)];  \
        STAGE_STMT;                                                             \
        VM_STMT;                                                                \
        BAR();                                                                  \
        __builtin_amdgcn_s_setprio(1);                                          \
        _Pragma("unroll") for (int kk = 0; kk < 2; ++kk)                        \
        _Pragma("unroll") for (int i = 0; i < 4; ++i)                           \
        _Pragma("unroll") for (int j = 0; j < 2; ++j)                           \
            acc[i][(P) * 2 + j] = __builtin_amdgcn_mfma_f32_16x16x32_bf16(      \
                ah[i][kk], bfr[j][kk], acc[i][(P) * 2 + j], 0, 0, 0);           \
        __builtin_amdgcn_s_setprio(0);                                          \
        BAR();                                                                  \
    }

        // prologue: tile0 {A,B01,B23} + tile1 {A,B01} = 5 units
        stA0(0); stB(0, 0); stB(0, 1);
        stA0(1); stB(1, 0);
        VMW(4);   // tile0 complete (2 newer units in flight)
        BAR();

        for (int t = 0; t < NT - 2; ++t) {
            M0PHASE(t, 0, stB(t + 1, 1), VMW(6))
            M0PHASE(t, 1, { stA0(t + 2); stB(t + 2, 0); }, VMW(6))
        }
        {   // t = NT-2
            const int t = NT - 2;
            M0PHASE(t, 0, stB(NT - 1, 1), VMW(6))
            M0PHASE(t, 1, , VMW(2))
        }
        {   // t = NT-1
            const int t = NT - 1;
            M0PHASE(t, 0, , VMW(0))
            M0PHASE(t, 1, , )
        }
#undef M0PHASE
    }
#undef VMW
#undef BAR

    const int wm = wr * WM;
    const int wn = wc * 64;

    if (MODE == 0) {
        float* Cf = (float*)C0;
#pragma unroll
        for (int i = 0; i < AI; ++i)
#pragma unroll
            for (int j = 0; j < 4; ++j)
#pragma unroll
                for (int r = 0; r < 4; ++r)
                    Cf[(size_t)(bm + wm + i * 16 + quad * 4 + r) * N + (bn + wn + j * 16 + l16)] =
                        acc[i][j][r];
    } else {
        // QKV routing; bn is a multiple of 256 so the whole block takes one branch
        u16* Qb = (u16*)C0;
        u16* Kb = (u16*)C1;
        u16* Vt = (u16*)C2;
        if (bn < 5120) {
            const bool isQ = bn < 4096;
            const float osc = isQ ? QSCALE_LOG2E : 1.0f;
#pragma unroll
            for (int i = 0; i < AI; ++i)
#pragma unroll
                for (int j = 0; j < 4; ++j) {
                    int n = bn + wn + j * 16 + l16;
                    int pp = (n & 127) >> 1;
                    bool odd = (l16 & 1);
#pragma unroll
                    for (int r = 0; r < 4; ++r) {
                        int m = bm + wm + i * 16 + quad * 4 + r;
                        float v = acc[i][j][r];
                        float u = __shfl_xor(v, 1);
                        float c = fc[m * 64 + pp];
                        float s = fs[m * 64 + pp];
                        float o = (odd ? (u * s + v * c) : (v * c - u * s)) * osc;
                        if (isQ)
                            Qb[(size_t)m * 4096 + n] = f2bf(o);
                        else
                            Kb[(size_t)m * 1024 + (n - 4096)] = f2bf(o);
                    }
                }
        } else {
            // V range: store transposed (d-major), no rope
#pragma unroll
            for (int i = 0; i < AI; ++i)
#pragma unroll
                for (int j = 0; j < 4; ++j) {
                    int n = bn + wn + j * 16 + l16;
                    ushort4 o;
                    o.x = f2bf(acc[i][j][0]);
                    o.y = f2bf(acc[i][j][1]);
                    o.z = f2bf(acc[i][j][2]);
                    o.w = f2bf(acc[i][j][3]);
                    *(ushort4*)&Vt[(size_t)(n - 5120) * SEQ + (bm + wm + i * 16 + quad * 4)] = o;
                }
        }
    }
}

// ---------------- Flash attention, S^T formulation (unchanged) ----------------
__global__ __launch_bounds__(256, 4) void attn_k(const u16* __restrict__ Q,
                                                 const u16* __restrict__ Kb,
                                                 const u16* __restrict__ Vt,
                                                 u16* __restrict__ Y) {
    __shared__ u16 Ks[64 * 128];   // swizzled: 16B chunks, slot = c ^ (row&15)
    __shared__ u16 Vs[128 * 64];   // swizzled: 16B chunks, slot = c ^ (row&7)
    __shared__ u16 Ps[4 * 16 * 64];// per-wave 2 KB; 8B chunks, c' = c ^ ((l16&7)<<1)
    const int tid = threadIdx.x;
    const int lane = tid & 63;
    const int w = tid >> 6;
    const int quad = lane >> 4;
    const int l16 = lane & 15;
    const int id = blockIdx.x;
    const int qt = 31 - (id >> 5);   // LPT: longest blocks first
    const int h = id & 31;
    const int kvh = h >> 2;
    const size_t qrow0 = (size_t)qt * 64;

    bf16_8 qf[4];
#pragma unroll
    for (int ks = 0; ks < 4; ++ks)
        qf[ks] = *(const bf16_8*)&Q[(qrow0 + w * 16 + l16) * DIM + h * HD + ks * 32 + quad * 8];

    f32x4 po[8] = {};    // 16 x 128 unnormalized output accumulator
    float lsum = 0.f;    // per-lane partial row sum for q-row l16

    char* psbase = (char*)Ps + w * 2048 + l16 * 128;  // this lane's P row
    const int sw = (l16 & 7) << 1;                    // 8B-chunk swizzle

    for (int kt = 0; kt <= qt; ++kt) {
#pragma unroll
        for (int r = 0; r < 4; ++r) {
            int S = r * 256 + tid;  // 0..1023
            {
                int row = S >> 4, slot = S & 15;
                int chunk = slot ^ (row & 15);
                const char* g = (const char*)Kb +
                    (((size_t)kt * 64 + row) * 1024 + kvh * HD + chunk * 8) * 2;
                async16(g, (char*)Ks + S * 16);
            }
            {
                int row = S >> 3, slot = S & 7;
                int chunk = slot ^ (row & 7);
                const char* g = (const char*)Vt +
                    (((size_t)(kvh * HD + row)) * SEQ + kt * 64 + chunk * 8) * 2;
                async16(g, (char*)Vs + S * 16);
            }
        }
        __syncthreads();

        f32x4 sc[4] = {};
#pragma unroll
        for (int ks = 0; ks < 4; ++ks)
#pragma unroll
            for (int jb = 0; jb < 4; ++jb) {
                bf16_8 kb = *(const bf16_8*)&Ks[(jb * 16 + l16) * 128 + ((ks * 4 + quad) ^ l16) * 8];
                sc[jb] = __builtin_amdgcn_mfma_f32_16x16x32_bf16(kb, qf[ks], sc[jb], 0, 0, 0);
            }

        float pv[4][4];
#pragma unroll
        for (int jb = 0; jb < 4; ++jb)
#pragma unroll
            for (int r = 0; r < 4; ++r)
                pv[jb][r] = exp2f(sc[jb][r]);

        if (kt == qt) {  // wave-uniform: mask k > q on the diagonal tile
            int qloc = w * 16 + l16;
#pragma unroll
            for (int jb = 0; jb < 4; ++jb)
#pragma unroll
                for (int r = 0; r < 4; ++r)
                    if (jb * 16 + quad * 4 + r > qloc) pv[jb][r] = 0.f;
        }

#pragma unroll
        for (int jb = 0; jb < 4; ++jb) {
            lsum += (pv[jb][0] + pv[jb][1]) + (pv[jb][2] + pv[jb][3]);
            ushort4 pk;
            pk.x = f2bf(pv[jb][0]);
            pk.y = f2bf(pv[jb][1]);
            pk.z = f2bf(pv[jb][2]);
            pk.w = f2bf(pv[jb][3]);
            int c = jb * 4 + quad;
            *(ushort4*)(psbase + ((c ^ sw) << 3)) = pk;
        }

#pragma unroll
        for (int ks = 0; ks < 2; ++ks) {
            int c = ks * 8 + quad * 2;
            bf16_8 pf = *(const bf16_8*)(psbase + ((c ^ sw) << 3));
#pragma unroll
            for (int n = 0; n < 8; ++n) {
                bf16_8 vf = *(const bf16_8*)&Vs[(n * 16 + l16) * 64 + (((ks * 4 + quad) ^ (l16 & 7))) * 8];
                po[n] = __builtin_amdgcn_mfma_f32_16x16x32_bf16(pf, vf, po[n], 0, 0, 0);
            }
        }
        __syncthreads();
    }

    lsum += __shfl_xor(lsum, 16);
    lsum += __shfl_xor(lsum, 32);
    float inv = 1.f / lsum;
#pragma unroll
    for (int r = 0; r < 4; ++r) {
        float invr = __shfl(inv, quad * 4 + r);
        size_t row = qrow0 + w * 16 + quad * 4 + r;
#pragma unroll
        for (int n = 0; n < 8; ++n)
            Y[row * DIM + h * HD + n * 16 + l16] = f2bf(po[n][r] * invr);
    }
}

extern "C" void kernel_launch(void* const* d_in, const int* in_sizes, int n_in,
                              void* d_out, int out_size, void* d_ws, size_t ws_size,
                              hipStream_t stream) {
    const float* x  = (const float*)d_in[0];
    const float* wq = (const float*)d_in[1];
    const float* wk = (const float*)d_in[2];
    const float* wv = (const float*)d_in[3];
    const float* wo = (const float*)d_in[4];
    const float* fc = (const float*)d_in[5];
    const float* fs = (const float*)d_in[6];

    char* ws = (char*)d_ws;
    const size_t MB = 1u << 20;
    u16* xb    = (u16*)(ws);             // 2048x4096 bf16       (16 MB)
    u16* wqkvb = (u16*)(ws + 16 * MB);   // 6144x4096 (wq|wk|wv) (48 MB)
    u16* wob   = (u16*)(ws + 64 * MB);   // 4096x4096            (32 MB)
    u16* Qb    = (u16*)(ws + 96 * MB);   // 2048x4096            (16 MB)
    u16* Kb    = (u16*)(ws + 112 * MB);  // 2048x1024            (4 MB)
    u16* Vtb   = (u16*)(ws + 116 * MB);  // 1024x2048 (V^T)      (4 MB)
    u16* Yb    = (u16*)(ws + 120 * MB);  // 2048x4096            (16 MB)

    const int sm1 = (2 * 256 * 64 + 2 * 256 * 64) * 2;  // 128 KB (MODE 1)
    const int sm0 = (2 * 128 * 64 + 2 * 256 * 64) * 2;  //  96 KB (MODE 0)
    static int inited = 0;
    if (!inited) {
        hipFuncSetAttribute(reinterpret_cast<const void*>(&gemm8p<1>),
                            hipFuncAttributeMaxDynamicSharedMemorySize, sm1);
        hipFuncSetAttribute(reinterpret_cast<const void*>(&gemm8p<0>),
                            hipFuncAttributeMaxDynamicSharedMemorySize, sm0);
        inited = 1;
    }

    // single fused cast: [x | wq | wk | wv | wo] -> bf16 at ws[0..96MB)
    cast_all<<<49152, 256, 0, stream>>>(x, wq, wk, wv, wo, (u16*)ws);

    // fused QKV projection + RoPE (+ Q pre-scale incl. log2e) epilogue
    gemm8p<1><<<dim3(24, 8), 512, sm1, stream>>>(xb, wqkvb, Qb, Kb, Vtb, fc, fs,
                                                 2048, 6144, 4096);

    // attention (LPT-ordered 1D grid)
    attn_k<<<dim3(1024), 256, 0, stream>>>(Qb, Kb, Vtb, Yb);

    // output projection -> fp32 d_out (BM=128, BN=256 -> 256 blocks, full chip)
    gemm8p<0><<<dim3(16, 16), 512, sm0, stream>>>(Yb, wob, (float*)d_out, nullptr, nullptr,
                                                  nullptr, nullptr, 2048, 4096, 4096);
}